// Round 3
// baseline (427.815 us; speedup 1.0000x reference)
//
#include <hip/hip_runtime.h>

#define BATCH  65536
#define NIN    9
#define NHID   100
#define TSTEPS 25
#define EPS    3e-5f

// ROUND-19: delete the 50-register accumulator array. R18 NULL result
// (VGPR pinned at 44 despite __launch_bounds__(256,4)) proves a0[25]/a1[25]
// are held in the AGPR bank with v_accvgpr_read/write moves on every
// accumulate — matching the ~2x gap between essential issue time (~15us)
// and measured VALU-busy (~29us). Fix: accumulate fc2 partials in LDS via
// ds_add_f32 (atomicAdd on __shared__, no-rtn). One plane per wave keeps
// the per-(t,lane) add order j=0..24 sequential (same-thread same-address
// atomics are program-ordered) -> bit-identical f32 partial sums; epilogue
// applies the SAME (q0+q1)+(q2+q3) butterfly + f64 m2 chain. Spike-gated
// (if(s){...}) so skipped steps add nothing (== adding d=0 exactly, no -0
// hazard: partials only ever reach +0 via RNE cancellation). Per-step VALU
// drops to sel+fma+cmp+min(abs mod free) = 4; accumulate traffic moves to
// the idle DS pipe (lane-stride-4B layout: 2-way bank alias = free).
__global__ __launch_bounds__(256, 2) void snn_kernel(
    const float* __restrict__ x,  const float* __restrict__ W1,
    const float* __restrict__ b1, const float* __restrict__ W2,
    const float* __restrict__ b2, float* __restrict__ out)
{
    __shared__ float sx[64 * NIN];                      // 2.25 KB staged x rows
    __shared__ __align__(16) float s0[4][TSTEPS][64];   // 25.6 KB a0 partials/wave
    __shared__ __align__(16) float s1[4][TSTEPS][64];   // 25.6 KB a1 partials/wave

    const int tid  = threadIdx.x;
    const int lane = tid & 63;
    const int wq   = __builtin_amdgcn_readfirstlane(tid >> 6);
    const int b0   = blockIdx.x * 64;

    // zero the accumulator planes: 1600 float4 per plane
    {
        const float4 z = make_float4(0.f, 0.f, 0.f, 0.f);
        float4* p0 = (float4*)&s0[0][0][0];
        float4* p1 = (float4*)&s1[0][0][0];
#pragma unroll
        for (int i = 0; i < 7; ++i) {                   // 7*256 = 1792 >= 1600
            const int idx = i * 256 + tid;
            if (idx < 4 * TSTEPS * 64 / 4) { p0[idx] = z; p1[idx] = z; }
        }
    }
    for (int i = tid; i < 64 * NIN; i += 256) sx[i] = x[(size_t)b0 * NIN + i];
    __syncthreads();

    // per-lane x row, f32 (exact input values)
    float xv[NIN];
#pragma unroll
    for (int i = 0; i < NIN; ++i) xv[i] = sx[lane * NIN + i];

    // per-(wave,lane) accumulator columns; t indexes fold to imm offsets
    float* const acc0 = &s0[wq][0][lane];
    float* const acc1 = &s1[wq][0][lane];

    const int h0 = wq * 25;
#pragma unroll 2
    for (int j = 0; j < 25; ++j) {
        const int h = h0 + j;                  // wave-uniform -> s_load weights
        float c32 = 0.f;
#pragma unroll
        for (int i = 0; i < NIN; ++i) c32 = fmaf(W1[h * NIN + i], xv[i], c32);
        c32 += b1[h];
        const float k  = c32 - 0.05f;          // u-chain: u = m-1
        const float k1 = c32 - 1.05f;
        const float w0 = W2[h], w1 = W2[NHID + h];

        float u = -1.0f, ming = 1e30f;
        bool  s = false;                       // spike(t-1) == reset(t)
#pragma unroll
        for (int t = 0; t < TSTEPS; ++t) {
            u = fmaf(0.95f, u, s ? k1 : k);    // leaky integrate + fused reset
            s = (u > 0.0f);                    // spike (== m > 1)
            ming = fminf(ming, fabsf(u));      // margin (abs modifier free)
            if (s) {                           // exec-masked; skip == add 0
                atomicAdd(acc0 + t * 64, w0);  // ds_add_f32, no-rtn
                atomicAdd(acc1 + t * 64, w1);
            }
        }

        // rare wave-uniform exact fallback: f32 replay vs EXACT f64 chain;
        // patch where decisions differ. Patch adds land after this j's main
        // adds and before j+1 -> same per-address order as the register
        // version (fmaf(sg,w,acc) == acc + (+-w) rounded once == ds_add).
        if (__any(ming < EPS)) {
            double c64 = 0.0;
#pragma unroll
            for (int i = 0; i < NIN; ++i)
                c64 += (double)W1[h * NIN + i] * (double)xv[i];
            c64 += (double)b1[h];
            const double c1 = c64 - 1.0;

            double md = 0.0;  bool sd = false;   // exact f64 chain
            float  ur = -1.0f; bool sr = false;  // f32 replay
#pragma unroll
            for (int t = 0; t < TSTEPS; ++t) {
                ur = fmaf(0.95f, ur, sr ? k1 : k);
                sr = (ur > 0.0f);
                md = 0.95 * md + (sd ? c1 : c64);
                sd = (md > 1.0);
                if (sr != sd) {                  // patch to the f64 decision
                    const float sg = sd ? 1.f : -1.f;
                    atomicAdd(acc0 + t * 64, sg * w0);
                    atomicAdd(acc1 + t * 64, sg * w1);
                }
            }
        }
    }
    __syncthreads();

    // wave0: cross-wave butterfly reduce (same bracketing as before) +
    // f64 mem2 chain, identical numerics.
    if (wq == 0) {
        double m20 = 0.0, m21 = 0.0;
        const double bb0 = (double)b2[0], bb1 = (double)b2[1];
#pragma unroll
        for (int t = 0; t < TSTEPS; ++t) {
            const float p00 = s0[0][t][lane], p01 = s0[1][t][lane];
            const float p02 = s0[2][t][lane], p03 = s0[3][t][lane];
            const float p10 = s1[0][t][lane], p11 = s1[1][t][lane];
            const float p12 = s1[2][t][lane], p13 = s1[3][t][lane];
            const float sum0 = (p00 + p01) + (p02 + p03);   // butterfly
            const float sum1 = (p10 + p11) + (p12 + p13);
            const double r0 = (m20 > 1.0) ? 1.0 : 0.0;
            const double r1 = (m21 > 1.0) ? 1.0 : 0.0;
            m20 = 0.95 * m20 + ((double)sum0 + bb0) - r0;
            m21 = 0.95 * m21 + ((double)sum1 + bb1) - r1;
            *(float2*)(out + ((size_t)t * BATCH + b0 + lane) * 2) =
                make_float2((float)m20, (float)m21);
        }
    }
}

extern "C" void kernel_launch(void* const* d_in, const int* in_sizes, int n_in,
                              void* d_out, int out_size, void* d_ws, size_t ws_size,
                              hipStream_t stream) {
    const float* x  = (const float*)d_in[0];
    const float* W1 = (const float*)d_in[1];
    const float* b1 = (const float*)d_in[2];
    const float* W2 = (const float*)d_in[3];
    const float* b2 = (const float*)d_in[4];
    float* out = (float*)d_out;

    dim3 grid(BATCH / 64), block(256);
    hipLaunchKernelGGL(snn_kernel, grid, block, 0, stream, x, W1, b1, W2, b2, out);
}

// Round 4
// 98.788 us; speedup vs baseline: 4.3307x; 4.3307x over previous
//
#include <hip/hip_runtime.h>

#define BATCH  65536
#define NIN    9
#define NHID   100
#define TSTEPS 25
#define CHUNK  5
#define EPS    3e-5f

typedef float v2f __attribute__((ext_vector_type(2)));

// ROUND-20: R17 structure + inline-asm accumulate. R19's LDS-atomic detour
// proved (a) ds_add_f32 can't carry the accumulate traffic (371us, VALU 8%)
// and (b) VGPR_Count reports ARCH vgprs only: it jumped 44->68 when the
// register arrays vanished => in R17 the 50-float a0/a1 arrays lived in the
// AGPR bank, paying v_accvgpr_read+write on every accumulate (~2500 extra
// VALU instr/thread — exactly the measured 29us busy vs ~18us essential).
// R18 proved attributes can't steer the allocator; asm operand constraints
// can: "+v"(acc) pins each accumulator to an architected VGPR at every use,
// "s"(w) pins the wave-uniform W2 weight to an SGPR (v_fmac_f32 src0=SGPR
// is legal, 1 sgpr read/instr). v_fmac_f32 acc,w,d == fmaf(d,w,acc) with
// d in {0,1}: bit-identical to R17. Budget 128 VGPR via launch_bounds(256,4)
// fits the ~75 live floats without AGPR splitting.
__global__ __launch_bounds__(256, 4) void snn_kernel(
    const float* __restrict__ x,  const float* __restrict__ W1,
    const float* __restrict__ b1, const float* __restrict__ W2,
    const float* __restrict__ b2, float* __restrict__ out)
{
    __shared__ float sx[64 * NIN];              // 2.25 KB staged x rows
    __shared__ v2f   sacc[2][4][CHUNK][64];     // 20.5 KB double-buffered reduce

    const int tid  = threadIdx.x;
    const int lane = tid & 63;
    const int wq   = __builtin_amdgcn_readfirstlane(tid >> 6);
    const int b0   = blockIdx.x * 64;

    for (int i = tid; i < 64 * NIN; i += 256) sx[i] = x[(size_t)b0 * NIN + i];
    __syncthreads();

    // per-lane x row, f32 (exact input values)
    float xv[NIN];
#pragma unroll
    for (int i = 0; i < NIN; ++i) xv[i] = sx[lane * NIN + i];

    // per-step fc2 partial sums: scalar floats, pinned to arch VGPRs by the
    // asm constraints below.
    float a0[TSTEPS], a1[TSTEPS];
#pragma unroll
    for (int t = 0; t < TSTEPS; ++t) { a0[t] = 0.f; a1[t] = 0.f; }

    const int h0 = wq * 25;
#pragma unroll 1
    for (int j = 0; j < 25; ++j) {
        const int h = h0 + j;                  // wave-uniform -> s_load weights
        float c32 = 0.f;
#pragma unroll
        for (int i = 0; i < NIN; ++i) c32 = fmaf(W1[h * NIN + i], xv[i], c32);
        c32 += b1[h];
        const float k  = c32 - 0.05f;          // u-chain: u = m-1
        const float k1 = c32 - 1.05f;
        const float w0 = W2[h], w1 = W2[NHID + h];

        float u = -1.0f, ming = 1e30f;
        bool  s = false;                       // spike(t-1) == reset(t)
#pragma unroll
        for (int t = 0; t < TSTEPS; ++t) {
            u = fmaf(0.95f, u, s ? k1 : k);    // leaky integrate + fused reset
            s = (u > 0.0f);                    // spike (== m > 1)
            ming = fminf(ming, fabsf(u));      // margin (abs modifier free)
            float d = s ? 1.f : 0.f;
            // acc += w*d, acc pinned to arch VGPR, w pinned to SGPR.
            asm("v_fmac_f32 %0, %1, %2" : "+v"(a0[t]) : "s"(w0), "v"(d));
            asm("v_fmac_f32 %0, %1, %2" : "+v"(a1[t]) : "s"(w1), "v"(d));
        }

        // rare wave-uniform exact fallback: f32 replay (bit-identical: same
        // fmaf sequence, same inputs) vs the EXACT f64 chain of rounds 2-14;
        // patch acc where decisions differ -> spike trains track the f64
        // numpy arbiter everywhere.
        if (__any(ming < EPS)) {
            double c64 = 0.0;
#pragma unroll
            for (int i = 0; i < NIN; ++i)
                c64 += (double)W1[h * NIN + i] * (double)xv[i];
            c64 += (double)b1[h];
            const double c1 = c64 - 1.0;

            double md = 0.0;  bool sd = false;   // exact f64 chain
            float  ur = -1.0f; bool sr = false;  // f32 replay
#pragma unroll
            for (int t = 0; t < TSTEPS; ++t) {
                ur = fmaf(0.95f, ur, sr ? k1 : k);
                sr = (ur > 0.0f);
                md = 0.95 * md + (sd ? c1 : c64);
                sd = (md > 1.0);
                if (sr != sd) {                  // patch to the f64 decision
                    float sg = sd ? 1.f : -1.f;
                    a0[t] = fmaf(sg, w0, a0[t]);
                    a1[t] = fmaf(sg, w1, a1[t]);
                }
            }
        }
    }

    // chunked cross-wave reduce + mem2 (wave 0), double-buffered LDS.
    // All acc indices compile-time constants (round-9 lesson).
    double m20 = 0.0, m21 = 0.0;
    double bb0 = (double)b2[0], bb1 = (double)b2[1];

#pragma unroll
    for (int k = 0; k < TSTEPS / CHUNK; ++k) {
#pragma unroll
        for (int u = 0; u < CHUNK; ++u)
            sacc[k & 1][wq][u][lane] = (v2f){a0[k * CHUNK + u], a1[k * CHUNK + u]};
        __syncthreads();
        // wave0 reads buf[k&1] before the NEXT barrier; other waves can't
        // overwrite buf[k&1] until chunk k+2's writes, behind that barrier.
        if (wq == 0) {
#pragma unroll
            for (int u = 0; u < CHUNK; ++u) {
                const int t = k * CHUNK + u;
                v2f q0 = sacc[k & 1][0][u][lane];
                v2f q1 = sacc[k & 1][1][u][lane];
                v2f q2 = sacc[k & 1][2][u][lane];
                v2f q3 = sacc[k & 1][3][u][lane];
                v2f sum = (q0 + q1) + (q2 + q3);   // butterfly bracketing
                double r0 = (m20 > 1.0) ? 1.0 : 0.0;
                double r1 = (m21 > 1.0) ? 1.0 : 0.0;
                m20 = 0.95 * m20 + ((double)sum[0] + bb0) - r0;
                m21 = 0.95 * m21 + ((double)sum[1] + bb1) - r1;
                *(float2*)(out + ((size_t)t * BATCH + b0 + lane) * 2) =
                    make_float2((float)m20, (float)m21);
            }
        }
    }
}

extern "C" void kernel_launch(void* const* d_in, const int* in_sizes, int n_in,
                              void* d_out, int out_size, void* d_ws, size_t ws_size,
                              hipStream_t stream) {
    const float* x  = (const float*)d_in[0];
    const float* W1 = (const float*)d_in[1];
    const float* b1 = (const float*)d_in[2];
    const float* W2 = (const float*)d_in[3];
    const float* b2 = (const float*)d_in[4];
    float* out = (float*)d_out;

    dim3 grid(BATCH / 64), block(256);
    hipLaunchKernelGGL(snn_kernel, grid, block, 0, stream, x, W1, b1, W2, b2, out);
}